// Round 9
// baseline (308.563 us; speedup 1.0000x reference)
//
#include <hip/hip_runtime.h>

#define NEG_SLOPE 0.2f
#define RSHIFT 5       // range width 32 dst nodes -> LDS-resident counting sort
#define RW     32
#define MAXNR  1600    // supports N <= 51200
#define CHUNKP 8192    // edges per partition block

__device__ __forceinline__ ushort f2bf(float f) {
    union { float f; unsigned u; } c; c.f = f;
    unsigned u = c.u;
    return (ushort)((u + 0x7fffu + ((u >> 16) & 1u)) >> 16);   // RNE
}
__device__ __forceinline__ float bflo(unsigned u) { return __uint_as_float(u << 16); }
__device__ __forceinline__ float bfhi(unsigned u) { return __uint_as_float(u & 0xffff0000u); }

// ---------------- mega: identical to R8 (frozen for attribution).
__global__ __launch_bounds__(256) void mega_kernel(
    const float* __restrict__ x, const float* __restrict__ wu,
    const float* __restrict__ bu, const float* __restrict__ wv,
    const int* __restrict__ s0, const int* __restrict__ d0,
    const int* __restrict__ s1, const int* __restrict__ d1,
    float* __restrict__ out, ushort* __restrict__ xbf,
    float* __restrict__ su, float* __restrict__ sv,
    int* __restrict__ gcur, unsigned* __restrict__ pairs,
    int N, int E, int nr, int cap, int scoreBlocks, int ppset)
{
    __shared__ __align__(16) float smemf[32 * 129 + 16 * 132];  // 24.96 KB
    int* smi = (int*)smemf;                   // role C alias (needs 3*MAXNR=4800)
    float* wlds = smemf;                      // weights 32x129
    float* xtile = smemf + 32 * 129;          // x rows  16x132 (pad -> 2-way)
    int tid = threadIdx.x;
    int bid = blockIdx.x;

    if (bid < 2 * ppset) {                    // ---- role C: partition edges
        int pb = bid;
        int t = pb / ppset, c = pb % ppset;
        const int* ss = t ? s1 : s0;
        const int* dd = t ? d1 : d0;
        int beg = c * CHUNKP, end = min(E, beg + CHUNKP);
        int* lcnt = smi; int* gb = smi + MAXNR; int* lrun = smi + 2 * MAXNR;
        for (int i = tid; i < nr; i += 256) lcnt[i] = 0;
        __syncthreads();
        for (int e = beg + tid; e < end; e += 256)
            atomicAdd(&lcnt[dd[e] >> RSHIFT], 1);
        __syncthreads();
        for (int i = tid; i < nr; i += 256) {
            gb[i] = atomicAdd(&gcur[t * nr + i], lcnt[i]);
            lrun[i] = 0;
        }
        __syncthreads();
        unsigned* pt = pairs + (size_t)t * nr * cap;
        for (int e = beg + tid; e < end; e += 256) {
            int dst = dd[e], src = ss[e];
            int rr = dst >> RSHIFT;
            int pos = atomicAdd(&lrun[rr], 1);
            pt[(size_t)rr * cap + gb[rr] + pos] = ((unsigned)dst << 16) | (unsigned)src;
        }
        return;
    }
    // ---- role B (fused): stage 16 rows + emit out/xbf, then scores from LDS
    int nb = bid - 2 * ppset;                 // 0..scoreBlocks-1
    int base = nb * 16;
    for (int i = tid; i < 4096; i += 256) {
        int o = i >> 7, k = i & 127;
        wlds[o * 129 + k] = (o < 16) ? wu[i] : wv[i - 2048];
    }
    for (int i2 = tid; i2 < 512; i2 += 256) { // 16 rows x 32 float4
        int I = nb * 512 + i2;                // global float4 index into x
        int nl = i2 >> 5, q = i2 & 31;
        int n = base + nl;
        float4 v = make_float4(0.f, 0.f, 0.f, 0.f);
        if (n < N) {
            v = ((const float4*)x)[I];
            ((float4*)out)[(size_t)n * 96 + q] = v;
            ushort4 b;
            b.x = f2bf(v.x); b.y = f2bf(v.y); b.z = f2bf(v.z); b.w = f2bf(v.w);
            *(ushort4*)(xbf + (size_t)I * 4) = b;
        }
        ((float4*)(xtile + nl * 132))[q] = v;
    }
    __syncthreads();
    int o = tid & 15;
    int nl = tid >> 4;
    int n = base + nl;
    if (n >= N) return;
    const float4* xr4 = (const float4*)(xtile + nl * 132);
    const float* wur = wlds + o * 129;
    const float* wvr = wlds + (16 + o) * 129;
    float au = 0.f, av = 0.f;
#pragma unroll
    for (int kk = 0; kk < 32; ++kk) {
        float4 xv = xr4[kk];
        int k = kk * 4;
        au = fmaf(xv.x, wur[k],     au);  av = fmaf(xv.x, wvr[k],     av);
        au = fmaf(xv.y, wur[k + 1], au);  av = fmaf(xv.y, wvr[k + 1], av);
        au = fmaf(xv.z, wur[k + 2], au);  av = fmaf(xv.z, wvr[k + 2], av);
        au = fmaf(xv.w, wur[k + 3], au);  av = fmaf(xv.w, wvr[k + 3], av);
    }
    float resu = au + bu[o];
    float resv = av;
    size_t toff = (o < 8) ? 0 : (size_t)N * 8;
    int ho = o & 7;
    su[toff + (size_t)n * 8 + ho] = resu;
    sv[toff + (size_t)n * 8 + ho] = resv;
}

// ---------------- buildagg: R8 sort + CROSS-NODE SOFTWARE PIPELINE.
// Per wave, node i+1's su/sv gathers are ISSUED before node i's acc phase,
// and FINISHED (exp + ev write, ping-pong buffer) after node i's epilogue.
// Hides the per-node serial e-phase gather chain under acc's FMAs/gathers.
// deg>32: 2nd slot group done inline in finish (P~1e-4). deg>64: serial
// fallback chunks (P~0). LDS 18.2KB -> still 8 blocks/CU.
__global__ __launch_bounds__(256, 8) void buildagg_kernel(
    const ushort* __restrict__ xbf, const float* __restrict__ su,
    const float* __restrict__ sv, const int* __restrict__ gcur,
    const unsigned* __restrict__ pairs, float* __restrict__ out,
    int N, int E, int nr, int cap)
{
    __shared__ ushort srcs[768];              // sorted src ids (cap <= 704)
    __shared__ int offl[33];
    __shared__ int cursor[32];
    __shared__ __align__(16) float ev8[4][2][512];  // per-wave ping-pong (16KB)
    int r = blockIdx.x, t = blockIdx.y, tid = threadIdx.x;
    int m = gcur[t * nr + r];
    if (m > cap) m = cap;                     // safety (never expected)
    const unsigned* p = pairs + ((size_t)t * nr + r) * cap;
    const float* sut = su + (size_t)t * N * 8;
    const float* svt = sv + (size_t)t * N * 8;

    unsigned* pl = (unsigned*)ev8;            // 16 KB >= cap*4 (2816 B)
    for (int i = tid; i < m; i += 256)        // stage pairs once (coalesced)
        pl[i] = p[i];
    if (tid < 32) cursor[tid] = 0;
    __syncthreads();
    for (int i = tid; i < m; i += 256)        // pass 1: histogram (local node id)
        atomicAdd(&cursor[(pl[i] >> 16) & (RW - 1)], 1);
    __syncthreads();
    if (tid < 32) {                           // 32-wide shfl scan -> offsets
        int v = cursor[tid];
        int incl = v;
#pragma unroll
        for (int d = 1; d < 32; d <<= 1) {
            int o = __shfl(incl, tid - d);
            if (tid >= d) incl += o;
        }
        offl[tid + 1] = incl;
        if (tid == 0) offl[0] = 0;
        cursor[tid] = incl - v;               // exclusive -> scatter cursor
    }
    __syncthreads();
    for (int i = tid; i < m; i += 256) {      // pass 2: scatter into LDS bucket
        unsigned v = pl[i];
        int pos = atomicAdd(&cursor[(v >> 16) & (RW - 1)], 1);
        srcs[pos] = (ushort)(v & 0xffffu);
    }
    __syncthreads();                          // ev8 free again after this point

    int wid = tid >> 6, lane = tid & 63;
    int g2 = lane >> 4, q16 = lane & 15;
    int j0 = q16 * 8;                         // 8 dims/lane, heads 0..7 in order
    int eg = lane >> 1;                       // e-phase: edge slot 0..31
    int hh = (lane & 1) * 4;                  // e-phase: head half {0,4}
    float* evw = &ev8[wid][0][0];

    // ---- pipeline state for the CURRENT node
    bool actC; int begC = 0, cntC = 0, par = 0;
    float4 l4C = make_float4(0.f, 0.f, 0.f, 0.f);
    // ---- prologue: issue + finish node 0 into buffer par=0
    {
        int n0 = (r << RSHIFT) + wid;
        actC = (n0 < N);
        float4 vh0 = make_float4(0.f, 0.f, 0.f, 0.f);
        float4 fu0 = make_float4(0.f, 0.f, 0.f, 0.f);
        int c1 = 0;
        if (actC) {
            begC = offl[wid];
            cntC = offl[wid + 1] - begC;
            c1 = min(cntC, 64);
            vh0 = *(const float4*)(svt + (size_t)n0 * 8 + hh);
            int sA = (int)srcs[begC + ((eg < c1) ? eg : 0)];
            if (c1 == 0) sA = 0;
            fu0 = *(const float4*)(sut + (size_t)sA * 8 + hh);
        }
        if (actC && cntC > 0) {
            float sx = fu0.x + vh0.x; sx = (sx >= 0.f) ? sx : NEG_SLOPE * sx;
            float sy = fu0.y + vh0.y; sy = (sy >= 0.f) ? sy : NEG_SLOPE * sy;
            float sz = fu0.z + vh0.z; sz = (sz >= 0.f) ? sz : NEG_SLOPE * sz;
            float sw = fu0.w + vh0.w; sw = (sw >= 0.f) ? sw : NEG_SLOPE * sw;
            bool vA = eg < c1;
            float4 ee;
            ee.x = vA ? __expf(sx) : 0.f;
            ee.y = vA ? __expf(sy) : 0.f;
            ee.z = vA ? __expf(sz) : 0.f;
            ee.w = vA ? __expf(sw) : 0.f;
            l4C = ee;
            *(float4*)(evw + eg * 8 + hh) = ee;
            if (c1 > 32) {                    // rare 2nd slot group, inline
                int e2 = 32 + eg;
                int s2 = (int)srcs[begC + ((e2 < c1) ? e2 : 0)];
                float4 fu2 = *(const float4*)(sut + (size_t)s2 * 8 + hh);
                float tx = fu2.x + vh0.x; tx = (tx >= 0.f) ? tx : NEG_SLOPE * tx;
                float ty = fu2.y + vh0.y; ty = (ty >= 0.f) ? ty : NEG_SLOPE * ty;
                float tz = fu2.z + vh0.z; tz = (tz >= 0.f) ? tz : NEG_SLOPE * tz;
                float tw = fu2.w + vh0.w; tw = (tw >= 0.f) ? tw : NEG_SLOPE * tw;
                bool vB = e2 < c1;
                float4 e2e;
                e2e.x = vB ? __expf(tx) : 0.f;
                e2e.y = vB ? __expf(ty) : 0.f;
                e2e.z = vB ? __expf(tz) : 0.f;
                e2e.w = vB ? __expf(tw) : 0.f;
                l4C.x += e2e.x; l4C.y += e2e.y; l4C.z += e2e.z; l4C.w += e2e.w;
                *(float4*)(evw + e2 * 8 + hh) = e2e;
            }
        }
    }

#pragma unroll 1
    for (int i = 0; i < 8; ++i) {
        bool lastN = (i == 7);
        // ---- ISSUE next node's gathers (land during acc/epilogue below)
        bool actN = false; int begN = 0, cntN = 0;
        float4 fuAn = make_float4(0.f, 0.f, 0.f, 0.f);
        float4 vhn  = make_float4(0.f, 0.f, 0.f, 0.f);
        if (!lastN) {
            int lnN = wid + 4 * (i + 1);
            int nN = (r << RSHIFT) + lnN;
            actN = (nN < N);
            if (actN) {
                begN = offl[lnN];
                cntN = offl[lnN + 1] - begN;
                int c1 = min(cntN, 64);
                vhn = *(const float4*)(svt + (size_t)nN * 8 + hh);
                int sA = (int)srcs[begN + ((eg < c1) ? eg : 0)];
                if (c1 == 0) sA = 0;
                fuAn = *(const float4*)(sut + (size_t)sA * 8 + hh);
            }
        }
        // ---- ACC current node
        float a0 = 0.f, a1 = 0.f, a2 = 0.f, a3 = 0.f;
        float a4 = 0.f, a5 = 0.f, a6 = 0.f, a7 = 0.f;
        float* evc = evw + par * 512;
        if (actC && cntC > 0) {
            int c1 = min(cntC, 64);
            int quads = (c1 + 3) >> 2;
            for (int i4 = 0; i4 < quads; i4 += 2) {   // 8 edges/iter/wave
                int e0 = (i4 << 2) + g2, e1 = e0 + 4;
                int sA = srcs[begC + ((e0 < c1) ? e0 : 0)];
                int sB = srcs[begC + ((e1 < c1) ? e1 : 0)];
                uint4 uA = *(const uint4*)(xbf + (size_t)sA * 128 + j0);
                uint4 uB = *(const uint4*)(xbf + (size_t)sB * 128 + j0);
                float4 pA0 = *(const float4*)(evc + e0 * 8);
                float4 pA1 = *(const float4*)(evc + e0 * 8 + 4);
                float4 pB0 = *(const float4*)(evc + e1 * 8);
                float4 pB1 = *(const float4*)(evc + e1 * 8 + 4);
                a0 = fmaf(bflo(uA.x), pA0.x, a0);
                a1 = fmaf(bfhi(uA.x), pA0.y, a1);
                a2 = fmaf(bflo(uA.y), pA0.z, a2);
                a3 = fmaf(bfhi(uA.y), pA0.w, a3);
                a4 = fmaf(bflo(uA.z), pA1.x, a4);
                a5 = fmaf(bfhi(uA.z), pA1.y, a5);
                a6 = fmaf(bflo(uA.w), pA1.z, a6);
                a7 = fmaf(bfhi(uA.w), pA1.w, a7);
                a0 = fmaf(bflo(uB.x), pB0.x, a0);
                a1 = fmaf(bfhi(uB.x), pB0.y, a1);
                a2 = fmaf(bflo(uB.y), pB0.z, a2);
                a3 = fmaf(bfhi(uB.y), pB0.w, a3);
                a4 = fmaf(bflo(uB.z), pB1.x, a4);
                a5 = fmaf(bfhi(uB.z), pB1.y, a5);
                a6 = fmaf(bflo(uB.w), pB1.z, a6);
                a7 = fmaf(bfhi(uB.w), pB1.w, a7);
            }
            // rare: deg > 64, remaining chunks serial (old path) into evc
            for (int cbeg = begC + 64; cbeg < begC + cntC; cbeg += 64) {
                int cnt = min(begC + cntC - cbeg, 64);
                int gmax = (cnt + 31) >> 5;
                for (int g = 0; g < gmax; ++g) {
                    int e = g * 32 + eg;
                    bool valid = e < cnt;
                    int sidx = srcs[cbeg + (valid ? e : 0)];
                    float4 fu = *(const float4*)(sut + (size_t)sidx * 8 + hh);
                    float4 vh4 = *(const float4*)(svt +
                        (size_t)((r << RSHIFT) + wid + 4 * i) * 8 + hh);
                    float sx = fu.x + vh4.x; sx = (sx >= 0.f) ? sx : NEG_SLOPE * sx;
                    float sy = fu.y + vh4.y; sy = (sy >= 0.f) ? sy : NEG_SLOPE * sy;
                    float sz = fu.z + vh4.z; sz = (sz >= 0.f) ? sz : NEG_SLOPE * sz;
                    float sw = fu.w + vh4.w; sw = (sw >= 0.f) ? sw : NEG_SLOPE * sw;
                    float4 ee;
                    ee.x = valid ? __expf(sx) : 0.f;
                    ee.y = valid ? __expf(sy) : 0.f;
                    ee.z = valid ? __expf(sz) : 0.f;
                    ee.w = valid ? __expf(sw) : 0.f;
                    l4C.x += ee.x; l4C.y += ee.y; l4C.z += ee.z; l4C.w += ee.w;
                    *(float4*)(evc + e * 8 + hh) = ee;
                }
                int q2 = (cnt + 3) >> 2;
                for (int i4 = 0; i4 < q2; i4 += 2) {
                    int e0 = (i4 << 2) + g2, e1 = e0 + 4;
                    int sA = srcs[cbeg + ((e0 < cnt) ? e0 : 0)];
                    int sB = srcs[cbeg + ((e1 < cnt) ? e1 : 0)];
                    uint4 uA = *(const uint4*)(xbf + (size_t)sA * 128 + j0);
                    uint4 uB = *(const uint4*)(xbf + (size_t)sB * 128 + j0);
                    float4 pA0 = *(const float4*)(evc + e0 * 8);
                    float4 pA1 = *(const float4*)(evc + e0 * 8 + 4);
                    float4 pB0 = *(const float4*)(evc + e1 * 8);
                    float4 pB1 = *(const float4*)(evc + e1 * 8 + 4);
                    a0 = fmaf(bflo(uA.x), pA0.x, a0);
                    a1 = fmaf(bfhi(uA.x), pA0.y, a1);
                    a2 = fmaf(bflo(uA.y), pA0.z, a2);
                    a3 = fmaf(bfhi(uA.y), pA0.w, a3);
                    a4 = fmaf(bflo(uA.z), pA1.x, a4);
                    a5 = fmaf(bfhi(uA.z), pA1.y, a5);
                    a6 = fmaf(bflo(uA.w), pA1.z, a6);
                    a7 = fmaf(bfhi(uA.w), pA1.w, a7);
                    a0 = fmaf(bflo(uB.x), pB0.x, a0);
                    a1 = fmaf(bfhi(uB.x), pB0.y, a1);
                    a2 = fmaf(bflo(uB.y), pB0.z, a2);
                    a3 = fmaf(bfhi(uB.y), pB0.w, a3);
                    a4 = fmaf(bflo(uB.z), pB1.x, a4);
                    a5 = fmaf(bfhi(uB.z), pB1.y, a5);
                    a6 = fmaf(bflo(uB.w), pB1.z, a6);
                    a7 = fmaf(bfhi(uB.w), pB1.w, a7);
                }
            }
        }
        // ---- EPILOGUE current node
        if (actC) {
            float4 l4 = l4C;
            l4.x += __shfl_xor(l4.x, 2);  l4.y += __shfl_xor(l4.y, 2);
            l4.z += __shfl_xor(l4.z, 2);  l4.w += __shfl_xor(l4.w, 2);
            l4.x += __shfl_xor(l4.x, 4);  l4.y += __shfl_xor(l4.y, 4);
            l4.z += __shfl_xor(l4.z, 4);  l4.w += __shfl_xor(l4.w, 4);
            l4.x += __shfl_xor(l4.x, 8);  l4.y += __shfl_xor(l4.y, 8);
            l4.z += __shfl_xor(l4.z, 8);  l4.w += __shfl_xor(l4.w, 8);
            l4.x += __shfl_xor(l4.x, 16); l4.y += __shfl_xor(l4.y, 16);
            l4.z += __shfl_xor(l4.z, 16); l4.w += __shfl_xor(l4.w, 16);
            l4.x += __shfl_xor(l4.x, 32); l4.y += __shfl_xor(l4.y, 32);
            l4.z += __shfl_xor(l4.z, 32); l4.w += __shfl_xor(l4.w, 32);
            float4 invl4;
            invl4.x = (l4.x > 0.f) ? (1.f / l4.x) : 0.f;
            invl4.y = (l4.y > 0.f) ? (1.f / l4.y) : 0.f;
            invl4.z = (l4.z > 0.f) ? (1.f / l4.z) : 0.f;
            invl4.w = (l4.w > 0.f) ? (1.f / l4.w) : 0.f;
            a0 += __shfl_xor(a0, 16); a0 += __shfl_xor(a0, 32);
            a1 += __shfl_xor(a1, 16); a1 += __shfl_xor(a1, 32);
            a2 += __shfl_xor(a2, 16); a2 += __shfl_xor(a2, 32);
            a3 += __shfl_xor(a3, 16); a3 += __shfl_xor(a3, 32);
            a4 += __shfl_xor(a4, 16); a4 += __shfl_xor(a4, 32);
            a5 += __shfl_xor(a5, 16); a5 += __shfl_xor(a5, 32);
            a6 += __shfl_xor(a6, 16); a6 += __shfl_xor(a6, 32);
            a7 += __shfl_xor(a7, 16); a7 += __shfl_xor(a7, 32);
            float ih0 = __shfl(invl4.x, 0);
            float ih1 = __shfl(invl4.y, 0);
            float ih2 = __shfl(invl4.z, 0);
            float ih3 = __shfl(invl4.w, 0);
            float ih4 = __shfl(invl4.x, 1);
            float ih5 = __shfl(invl4.y, 1);
            float ih6 = __shfl(invl4.z, 1);
            float ih7 = __shfl(invl4.w, 1);
            if (g2 == 0) {
                int n = (r << RSHIFT) + wid + 4 * i;
                float* op = out + (size_t)n * 384 + 128 + (size_t)t * 128 + j0;
                *(float4*)op       = make_float4(a0 * ih0, a1 * ih1, a2 * ih2, a3 * ih3);
                *(float4*)(op + 4) = make_float4(a4 * ih4, a5 * ih5, a6 * ih6, a7 * ih7);
            }
        }
        // ---- FINISH next node into buffer par^1
        float4 l4n = make_float4(0.f, 0.f, 0.f, 0.f);
        if (!lastN && actN && cntN > 0) {
            float* evn = evw + (par ^ 1) * 512;
            int c1 = min(cntN, 64);
            float sx = fuAn.x + vhn.x; sx = (sx >= 0.f) ? sx : NEG_SLOPE * sx;
            float sy = fuAn.y + vhn.y; sy = (sy >= 0.f) ? sy : NEG_SLOPE * sy;
            float sz = fuAn.z + vhn.z; sz = (sz >= 0.f) ? sz : NEG_SLOPE * sz;
            float sw = fuAn.w + vhn.w; sw = (sw >= 0.f) ? sw : NEG_SLOPE * sw;
            bool vA = eg < c1;
            float4 ee;
            ee.x = vA ? __expf(sx) : 0.f;
            ee.y = vA ? __expf(sy) : 0.f;
            ee.z = vA ? __expf(sz) : 0.f;
            ee.w = vA ? __expf(sw) : 0.f;
            l4n = ee;
            *(float4*)(evn + eg * 8 + hh) = ee;
            if (c1 > 32) {                    // rare 2nd slot group, inline
                int e2 = 32 + eg;
                int s2 = (int)srcs[begN + ((e2 < c1) ? e2 : 0)];
                float4 fu2 = *(const float4*)(sut + (size_t)s2 * 8 + hh);
                float tx = fu2.x + vhn.x; tx = (tx >= 0.f) ? tx : NEG_SLOPE * tx;
                float ty = fu2.y + vhn.y; ty = (ty >= 0.f) ? ty : NEG_SLOPE * ty;
                float tz = fu2.z + vhn.z; tz = (tz >= 0.f) ? tz : NEG_SLOPE * tz;
                float tw = fu2.w + vhn.w; tw = (tw >= 0.f) ? tw : NEG_SLOPE * tw;
                bool vB = e2 < c1;
                float4 e2e;
                e2e.x = vB ? __expf(tx) : 0.f;
                e2e.y = vB ? __expf(ty) : 0.f;
                e2e.z = vB ? __expf(tz) : 0.f;
                e2e.w = vB ? __expf(tw) : 0.f;
                l4n.x += e2e.x; l4n.y += e2e.y; l4n.z += e2e.z; l4n.w += e2e.w;
                *(float4*)(evn + e2 * 8 + hh) = e2e;
            }
        }
        // ---- shift pipeline state
        actC = actN; begC = begN; cntC = cntN; l4C = l4n; par ^= 1;
    }
}

extern "C" void kernel_launch(void* const* d_in, const int* in_sizes, int n_in,
                              void* d_out, int out_size, void* d_ws, size_t ws_size,
                              hipStream_t stream)
{
    const float* x  = (const float*)d_in[0];
    const float* wu = (const float*)d_in[1];
    const float* bu = (const float*)d_in[2];
    const float* wv = (const float*)d_in[3];
    const int* s0 = (const int*)d_in[4];
    const int* d0 = (const int*)d_in[5];
    const int* s1 = (const int*)d_in[6];
    const int* d1 = (const int*)d_in[7];
    float* out = (float*)d_out;
    int N = in_sizes[0] / 128;
    int E = in_sizes[4];

    int nr = ((N - 1) >> RSHIFT) + 1;               // 1563 for N=50000 (<= MAXNR)
    long long mean = (long long)RW * E / N;         // ~512
    int cap = (int)(mean + mean / 4 + 64);          // 704 (>8 sigma margin)

    char* ws = (char*)d_ws;
    size_t o = 0;
    auto alloc = [&](size_t bytes) -> void* {
        void* p = ws + o;
        o = (o + bytes + 255) & ~(size_t)255;
        return p;
    };
    float* su       = (float*)alloc((size_t)N * 16 * 4);   // [2][N][8] t-major
    float* sv       = (float*)alloc((size_t)N * 16 * 4);   // [2][N][8] t-major
    int* gcur       = (int*)alloc((size_t)2 * nr * 4);
    unsigned* pairs = (unsigned*)alloc((size_t)2 * nr * cap * 4);
    ushort* xbf     = (ushort*)alloc((size_t)N * 128 * 2);

    int scoreBlocks = (N + 15) / 16;                // 3125
    int ppset       = (E + CHUNKP - 1) / CHUNKP;    // 98

    hipMemsetAsync(gcur, 0, (size_t)2 * nr * 4, stream);
    mega_kernel<<<scoreBlocks + 2 * ppset, 256, 0, stream>>>(
        x, wu, bu, wv, s0, d0, s1, d1, out, xbf, su, sv,
        gcur, pairs, N, E, nr, cap, scoreBlocks, ppset);
    buildagg_kernel<<<dim3(nr, 2), 256, 0, stream>>>(
        xbf, su, sv, gcur, pairs, out, N, E, nr, cap);
}